// Round 5
// baseline (3458.450 us; speedup 1.0000x reference)
//
#include <hip/hip_runtime.h>
#include <cstdint>
#include <cstddef>

// SNN_53618371723788: 2-layer SLSTM, B=65536, T=24, H=64, fp32.
// Pass 1: layer-1 recurrence, emits spike bitmasks (ballot) + final mem1 to d_ws.
// Pass 2: layer-2 recurrence (spikes as SGPR bitmasks) + extra step + fused Wout GEMV.
// d_ws usage: 24*65536*8 B spike masks + 65536*64*4 B mem1 = 29,360,128 B.
//
// R5: __launch_bounds__(512,1) -> unambiguous 512-VGPR budget (R4's (512,2)
// still allocated only 88 VGPRs; occupancy is LDS-capped at 1 block/CU for
// pass2 regardless, so a ~130-reg allocation is free). pass2's p0/p1 per-t
// accumulators replaced by per-lane spike-bit registers (sb[b] bit t), with
// the identical fmaf chain replayed in the epilogue -> -24 live VGPRs in the
// hot t-loop, bit-exact (same values, same fma order).

#define BB 65536
#define TT 24
#define NB 8  // batch elements per wave

__device__ __forceinline__ float bcastf(float v, int l) {
  return __int_as_float(__builtin_amdgcn_readlane(__float_as_int(v), l));
}
__device__ __forceinline__ float sigm(float v) { return 1.0f / (1.0f + expf(-v)); }
__device__ __forceinline__ float wsum(float v) {
#pragma unroll
  for (int o = 32; o > 0; o >>= 1) v += __shfl_xor(v, o);
  return v;
}

__global__ __launch_bounds__(512, 1) void snn_pass1(
    const float* __restrict__ x, const float* __restrict__ Wih1,
    const float* __restrict__ Whh1, const float* __restrict__ bih1,
    const float* __restrict__ bhh1, const float* __restrict__ thr1p,
    unsigned long long* __restrict__ spk_out, float* __restrict__ mem1_out) {
  // P1[m][j] = {Whh1[j][m], Whh1[64+j][m], Whh1[128+j][m], Whh1[192+j][m]}
  __shared__ float4 P1[64][64];  // 64 KB
  int tid = threadIdx.x;
  for (int idx = tid; idx < 16384; idx += 512) {
    int k = idx >> 6, m = idx & 63;
    ((float*)&P1[m][k & 63])[k >> 6] = Whh1[idx];
  }
  __syncthreads();
  int lane = tid & 63, wave = tid >> 6;
  int wb = (blockIdx.x * 8 + wave) * NB;  // first batch of this wave
  float thr1 = thr1p[0];
  float b1q[4], wq[4];
#pragma unroll
  for (int q = 0; q < 4; q++) {
    b1q[q] = bih1[q * 64 + lane] + bhh1[q * 64 + lane];
    wq[q] = Wih1[q * 64 + lane];
  }
  float syn[NB], mem[NB];
#pragma unroll
  for (int b = 0; b < NB; b++) { syn[b] = 0.0f; mem[b] = 0.0f; }

  for (int t = 0; t < TT; t++) {
    float acc[NB][4];
#pragma unroll
    for (int b = 0; b < NB; b++) {
      float xbt = x[(wb + b) * TT + t];
#pragma unroll
      for (int q = 0; q < 4; q++) acc[b][q] = fmaf(xbt, wq[q], b1q[q]);
    }
#pragma unroll 8
    for (int m = 0; m < 64; m++) {
      float4 w = P1[m][lane];  // one ds_read_b128 serves 8 batches x 4 gates
#pragma unroll
      for (int b = 0; b < NB; b++) {
        float s = bcastf(mem[b], m);  // readlane -> SGPR operand
        acc[b][0] = fmaf(s, w.x, acc[b][0]);
        acc[b][1] = fmaf(s, w.y, acc[b][1]);
        acc[b][2] = fmaf(s, w.z, acc[b][2]);
        acc[b][3] = fmaf(s, w.w, acc[b][3]);
      }
    }
    unsigned long long myspk = 0;  // lane b keeps batch b's ballot (uniform value)
#pragma unroll
    for (int b = 0; b < NB; b++) {
      float ig = sigm(acc[b][0]), fg = sigm(acc[b][1]);
      float gg = tanhf(acc[b][2]), og = sigm(acc[b][3]);
      float sn = fmaf(fg, syn[b], ig * gg);
      float rst = (mem[b] > thr1) ? thr1 : 0.0f;  // reset uses OLD mem
      float mn = fmaf(og, tanhf(sn), -rst);
      syn[b] = sn;
      mem[b] = mn;
      unsigned long long msk = __ballot(mn > thr1);  // wave-uniform
      if (lane == b) myspk = msk;
    }
    if (lane < NB)
      spk_out[(size_t)t * BB + wb + lane] = myspk;
  }
#pragma unroll
  for (int b = 0; b < NB; b++)
    mem1_out[(size_t)(wb + b) * 64 + lane] = mem[b];
}

__global__ __launch_bounds__(512, 1) void snn_pass2(
    const float* __restrict__ Wih2, const float* __restrict__ Whh2,
    const float* __restrict__ bih2, const float* __restrict__ bhh2,
    const float* __restrict__ thr2p, const float* __restrict__ Wout,
    const float* __restrict__ bout,
    const unsigned long long* __restrict__ spk_in,
    const float* __restrict__ mem1_in, float* __restrict__ out) {
  __shared__ float4 Pih[64][64];  // 64 KB
  __shared__ float4 Phh[64][64];  // 64 KB (gfx950: 160 KB LDS per workgroup)
  int tid = threadIdx.x;
  for (int idx = tid; idx < 16384; idx += 512) {
    int k = idx >> 6, m = idx & 63;
    ((float*)&Pih[m][k & 63])[k >> 6] = Wih2[idx];
    ((float*)&Phh[m][k & 63])[k >> 6] = Whh2[idx];
  }
  __syncthreads();
  int lane = tid & 63, wave = tid >> 6;
  int wb = (blockIdx.x * 8 + wave) * NB;
  float thr2 = thr2p[0];
  float b2q[4];
#pragma unroll
  for (int q = 0; q < 4; q++) b2q[q] = bih2[q * 64 + lane] + bhh2[q * 64 + lane];
  float syn[NB], mem[NB];
  unsigned sb[NB];  // per-lane spike history of THIS lane's neuron, bit t
#pragma unroll
  for (int b = 0; b < NB; b++) { syn[b] = 0.0f; mem[b] = 0.0f; sb[b] = 0u; }

  for (int t = 0; t < TT; t++) {
    // spike masks are wave-uniform -> force into SGPRs (SALU bit extract, no VGPRs)
    unsigned mlo[NB], mhi[NB];
#pragma unroll
    for (int b = 0; b < NB; b++) {
      unsigned long long v = spk_in[(size_t)t * BB + wb + b];
      mlo[b] = __builtin_amdgcn_readfirstlane((unsigned)v);
      mhi[b] = __builtin_amdgcn_readfirstlane((unsigned)(v >> 32));
    }
    float acc[NB][4];
#pragma unroll
    for (int b = 0; b < NB; b++) {
#pragma unroll
      for (int q = 0; q < 4; q++) acc[b][q] = b2q[q];
    }
#pragma unroll 4
    for (int m = 0; m < 64; m++) {
      float4 wi = Pih[m][lane];
      float4 wh = Phh[m][lane];
#pragma unroll
      for (int b = 0; b < NB; b++) {
        unsigned bits = (m < 32) ? mlo[b] : mhi[b];          // s_cselect
        float s1 = ((bits >> (m & 31)) & 1u) ? 1.0f : 0.0f;  // s_lshr+s_cselect
        float s2 = bcastf(mem[b], m);
        acc[b][0] = fmaf(s1, wi.x, fmaf(s2, wh.x, acc[b][0]));
        acc[b][1] = fmaf(s1, wi.y, fmaf(s2, wh.y, acc[b][1]));
        acc[b][2] = fmaf(s1, wi.z, fmaf(s2, wh.z, acc[b][2]));
        acc[b][3] = fmaf(s1, wi.w, fmaf(s2, wh.w, acc[b][3]));
      }
    }
#pragma unroll
    for (int b = 0; b < NB; b++) {
      float ig = sigm(acc[b][0]), fg = sigm(acc[b][1]);
      float gg = tanhf(acc[b][2]), og = sigm(acc[b][3]);
      float sn = fmaf(fg, syn[b], ig * gg);
      float rst = (mem[b] > thr2) ? thr2 : 0.0f;
      float mn = fmaf(og, tanhf(sn), -rst);
      syn[b] = sn;
      mem[b] = mn;
      sb[b] |= (mn > thr2) ? (1u << t) : 0u;  // record spk2 bit; p-sums replayed in epilogue
    }
  }

  // extra step: input = final mem1 (dense)
  float m1[NB];
#pragma unroll
  for (int b = 0; b < NB; b++) m1[b] = mem1_in[(size_t)(wb + b) * 64 + lane];
  float acc[NB][4];
#pragma unroll
  for (int b = 0; b < NB; b++) {
#pragma unroll
    for (int q = 0; q < 4; q++) acc[b][q] = b2q[q];
  }
#pragma unroll 4
  for (int m = 0; m < 64; m++) {
    float4 wi = Pih[m][lane];
    float4 wh = Phh[m][lane];
#pragma unroll
    for (int b = 0; b < NB; b++) {
      float s1 = bcastf(m1[b], m);
      float s2 = bcastf(mem[b], m);
      acc[b][0] = fmaf(s1, wi.x, fmaf(s2, wh.x, acc[b][0]));
      acc[b][1] = fmaf(s1, wi.y, fmaf(s2, wh.y, acc[b][1]));
      acc[b][2] = fmaf(s1, wi.z, fmaf(s2, wh.z, acc[b][2]));
      acc[b][3] = fmaf(s1, wi.w, fmaf(s2, wh.w, acc[b][3]));
    }
  }
  // epilogue: replay p0/p1 accumulation (identical fmaf order to R4: t=0..23,
  // then spk2_last (wA), then mem2 (wB)) from the recorded spike bits.
  float p0[NB], p1[NB];
#pragma unroll
  for (int b = 0; b < NB; b++) { p0[b] = 0.0f; p1[b] = 0.0f; }
#pragma unroll 4
  for (int t = 0; t < TT; t++) {
    float w0 = Wout[t * 64 + lane];
    float w1 = Wout[1664 + t * 64 + lane];
#pragma unroll
    for (int b = 0; b < NB; b++) {
      float sf = ((sb[b] >> t) & 1u) ? 1.0f : 0.0f;
      p0[b] = fmaf(sf, w0, p0[b]);
      p1[b] = fmaf(sf, w1, p1[b]);
    }
  }
  float wA0 = Wout[1536 + lane], wA1 = Wout[1664 + 1536 + lane];  // spk2_last
  float wB0 = Wout[1600 + lane], wB1 = Wout[1664 + 1600 + lane];  // mem2 final
  float bo0 = bout[0], bo1 = bout[1];
#pragma unroll
  for (int b = 0; b < NB; b++) {
    float ig = sigm(acc[b][0]), fg = sigm(acc[b][1]);
    float gg = tanhf(acc[b][2]), og = sigm(acc[b][3]);
    float sn = fmaf(fg, syn[b], ig * gg);
    float rst = (mem[b] > thr2) ? thr2 : 0.0f;
    float mn = fmaf(og, tanhf(sn), -rst);
    float sf = (mn > thr2) ? 1.0f : 0.0f;
    p0[b] = fmaf(sf, wA0, p0[b]);
    p1[b] = fmaf(sf, wA1, p1[b]);
    p0[b] = fmaf(mn, wB0, p0[b]);
    p1[b] = fmaf(mn, wB1, p1[b]);
  }
  // cross-lane reduce; wsum leaves the full sum in ALL lanes (uniform),
  // so lane 2b / 2b+1 just keep their own output via predicated assign.
  float vout = 0.0f;
#pragma unroll
  for (int b = 0; b < NB; b++) {
    float r0 = wsum(p0[b]);
    float r1 = wsum(p1[b]);
    if (lane == 2 * b) vout = r0;
    if (lane == 2 * b + 1) vout = r1;
  }
  if (lane < 2 * NB)
    out[(size_t)wb * 2 + lane] = vout + ((lane & 1) ? bo1 : bo0);
}

extern "C" void kernel_launch(void* const* d_in, const int* in_sizes, int n_in,
                              void* d_out, int out_size, void* d_ws, size_t ws_size,
                              hipStream_t stream) {
  const float* x = (const float*)d_in[0];
  const float* Wih1 = (const float*)d_in[1];
  const float* Whh1 = (const float*)d_in[2];
  const float* bih1 = (const float*)d_in[3];
  const float* bhh1 = (const float*)d_in[4];
  const float* thr1 = (const float*)d_in[5];
  const float* Wih2 = (const float*)d_in[6];
  const float* Whh2 = (const float*)d_in[7];
  const float* bih2 = (const float*)d_in[8];
  const float* bhh2 = (const float*)d_in[9];
  const float* thr2 = (const float*)d_in[10];
  const float* Wout = (const float*)d_in[11];
  const float* bout = (const float*)d_in[12];

  unsigned long long* spk = (unsigned long long*)d_ws;
  float* mem1 = (float*)((char*)d_ws + (size_t)TT * BB * 8);

  const int grid = BB / (8 * NB);  // 1024 blocks of 512 threads (8 waves x 8 batches)
  snn_pass1<<<grid, 512, 0, stream>>>(x, Wih1, Whh1, bih1, bhh1, thr1, spk, mem1);
  snn_pass2<<<grid, 512, 0, stream>>>(Wih2, Whh2, bih2, bhh2, thr2, Wout, bout,
                                      spk, mem1, (float*)d_out);
}

// Round 6
// 2701.538 us; speedup vs baseline: 1.2802x; 1.2802x over previous
//
#include <hip/hip_runtime.h>
#include <cstdint>
#include <cstddef>

// SNN_53618371723788: 2-layer SLSTM, B=65536, T=24, H=64, fp32.
// Pass 1: layer-1 recurrence, emits spike bitmasks (ballot) + final mem1 to d_ws.
// Pass 2: layer-2 recurrence (spikes as SGPR bitmasks) + extra step + fused Wout GEMV.
// d_ws usage: 24*65536*8 B spike masks + 65536*64*4 B mem1 = 29,360,128 B.
//
// R6: replace v_readlane state broadcast with LDS same-address broadcast.
// R5 proved the ~2.8x VALU inflation is NOT register pressure (VGPR=88 under a
// 512 budget). Suspect: v_readlane writes an SGPR consumed by the next v_fma
// (VALU->SGPR->VALU hazard = s_nop wait states, x512/t). Now: each wave stages
// mem[b] into a private LDS strip (8 ds_write/t), m-loop reads 8 state values
// via two broadcast ds_read_b128 (same address all lanes, conflict-free, LDS
// pipe co-issues with VALU, all-VGPR fma operands). Identical values ->
// bit-exact. Extra step (4% of work) keeps readlane form.

#define BB 65536
#define TT 24
#define NB 8  // batch elements per wave

__device__ __forceinline__ float bcastf(float v, int l) {
  return __int_as_float(__builtin_amdgcn_readlane(__float_as_int(v), l));
}
__device__ __forceinline__ float sigm(float v) { return 1.0f / (1.0f + expf(-v)); }
__device__ __forceinline__ float wsum(float v) {
#pragma unroll
  for (int o = 32; o > 0; o >>= 1) v += __shfl_xor(v, o);
  return v;
}

__global__ __launch_bounds__(512, 4) void snn_pass1(
    const float* __restrict__ x, const float* __restrict__ Wih1,
    const float* __restrict__ Whh1, const float* __restrict__ bih1,
    const float* __restrict__ bhh1, const float* __restrict__ thr1p,
    unsigned long long* __restrict__ spk_out, float* __restrict__ mem1_out) {
  // P1[m][j] = {Whh1[j][m], Whh1[64+j][m], Whh1[128+j][m], Whh1[192+j][m]}
  __shared__ float4 P1[64][64];     // 64 KB
  __shared__ float stM[8][64][NB];  // 16 KB: per-wave state broadcast strip
  int tid = threadIdx.x;
  for (int idx = tid; idx < 16384; idx += 512) {
    int k = idx >> 6, m = idx & 63;
    ((float*)&P1[m][k & 63])[k >> 6] = Whh1[idx];
  }
  __syncthreads();
  int lane = tid & 63, wave = tid >> 6;
  int wb = (blockIdx.x * 8 + wave) * NB;  // first batch of this wave
  float thr1 = thr1p[0];
  float b1q[4], wq[4];
#pragma unroll
  for (int q = 0; q < 4; q++) {
    b1q[q] = bih1[q * 64 + lane] + bhh1[q * 64 + lane];
    wq[q] = Wih1[q * 64 + lane];
  }
  float syn[NB], mem[NB];
#pragma unroll
  for (int b = 0; b < NB; b++) { syn[b] = 0.0f; mem[b] = 0.0f; }

  for (int t = 0; t < TT; t++) {
    // stage this wave's mem state: lane j holds neuron j for all 8 batches
#pragma unroll
    for (int b = 0; b < NB; b++) stM[wave][lane][b] = mem[b];
    float acc[NB][4];
#pragma unroll
    for (int b = 0; b < NB; b++) {
      float xbt = x[(wb + b) * TT + t];
#pragma unroll
      for (int q = 0; q < 4; q++) acc[b][q] = fmaf(xbt, wq[q], b1q[q]);
    }
#pragma unroll 8
    for (int m = 0; m < 64; m++) {
      float4 w = P1[m][lane];  // per-lane weights (ds_read_b128)
      float4 sa = *(const float4*)&stM[wave][m][0];  // broadcast: same addr all lanes
      float4 sb = *(const float4*)&stM[wave][m][4];
      float s[NB] = {sa.x, sa.y, sa.z, sa.w, sb.x, sb.y, sb.z, sb.w};
#pragma unroll
      for (int b = 0; b < NB; b++) {
        acc[b][0] = fmaf(s[b], w.x, acc[b][0]);
        acc[b][1] = fmaf(s[b], w.y, acc[b][1]);
        acc[b][2] = fmaf(s[b], w.z, acc[b][2]);
        acc[b][3] = fmaf(s[b], w.w, acc[b][3]);
      }
    }
    unsigned long long myspk = 0;  // lane b keeps batch b's ballot (uniform value)
#pragma unroll
    for (int b = 0; b < NB; b++) {
      float ig = sigm(acc[b][0]), fg = sigm(acc[b][1]);
      float gg = tanhf(acc[b][2]), og = sigm(acc[b][3]);
      float sn = fmaf(fg, syn[b], ig * gg);
      float rst = (mem[b] > thr1) ? thr1 : 0.0f;  // reset uses OLD mem
      float mn = fmaf(og, tanhf(sn), -rst);
      syn[b] = sn;
      mem[b] = mn;
      unsigned long long msk = __ballot(mn > thr1);  // wave-uniform
      if (lane == b) myspk = msk;
    }
    if (lane < NB)
      spk_out[(size_t)t * BB + wb + lane] = myspk;
  }
#pragma unroll
  for (int b = 0; b < NB; b++)
    mem1_out[(size_t)(wb + b) * 64 + lane] = mem[b];
}

__global__ __launch_bounds__(512, 2) void snn_pass2(
    const float* __restrict__ Wih2, const float* __restrict__ Whh2,
    const float* __restrict__ bih2, const float* __restrict__ bhh2,
    const float* __restrict__ thr2p, const float* __restrict__ Wout,
    const float* __restrict__ bout,
    const unsigned long long* __restrict__ spk_in,
    const float* __restrict__ mem1_in, float* __restrict__ out) {
  __shared__ float4 Pih[64][64];    // 64 KB
  __shared__ float4 Phh[64][64];    // 64 KB
  __shared__ float stM[8][64][NB];  // 16 KB -> 144 KB total (1 block/CU)
  int tid = threadIdx.x;
  for (int idx = tid; idx < 16384; idx += 512) {
    int k = idx >> 6, m = idx & 63;
    ((float*)&Pih[m][k & 63])[k >> 6] = Wih2[idx];
    ((float*)&Phh[m][k & 63])[k >> 6] = Whh2[idx];
  }
  __syncthreads();
  int lane = tid & 63, wave = tid >> 6;
  int wb = (blockIdx.x * 8 + wave) * NB;
  float thr2 = thr2p[0];
  float b2q[4];
#pragma unroll
  for (int q = 0; q < 4; q++) b2q[q] = bih2[q * 64 + lane] + bhh2[q * 64 + lane];
  float syn[NB], mem[NB];
  unsigned sb8[NB];  // per-lane spike history of THIS lane's neuron, bit t
#pragma unroll
  for (int b = 0; b < NB; b++) { syn[b] = 0.0f; mem[b] = 0.0f; sb8[b] = 0u; }

  for (int t = 0; t < TT; t++) {
    // spike masks are wave-uniform -> SGPRs (SALU bit extract, co-issues)
    unsigned mlo[NB], mhi[NB];
#pragma unroll
    for (int b = 0; b < NB; b++) {
      unsigned long long v = spk_in[(size_t)t * BB + wb + b];
      mlo[b] = __builtin_amdgcn_readfirstlane((unsigned)v);
      mhi[b] = __builtin_amdgcn_readfirstlane((unsigned)(v >> 32));
    }
    // stage mem state for LDS broadcast
#pragma unroll
    for (int b = 0; b < NB; b++) stM[wave][lane][b] = mem[b];
    float acc[NB][4];
#pragma unroll
    for (int b = 0; b < NB; b++) {
#pragma unroll
      for (int q = 0; q < 4; q++) acc[b][q] = b2q[q];
    }
#pragma unroll 4
    for (int m = 0; m < 64; m++) {
      float4 wi = Pih[m][lane];
      float4 wh = Phh[m][lane];
      float4 sa = *(const float4*)&stM[wave][m][0];  // broadcast reads
      float4 sbv = *(const float4*)&stM[wave][m][4];
      float s[NB] = {sa.x, sa.y, sa.z, sa.w, sbv.x, sbv.y, sbv.z, sbv.w};
#pragma unroll
      for (int b = 0; b < NB; b++) {
        unsigned bits = (m < 32) ? mlo[b] : mhi[b];          // s_cselect
        float s1 = ((bits >> (m & 31)) & 1u) ? 1.0f : 0.0f;  // SALU select
        acc[b][0] = fmaf(s1, wi.x, fmaf(s[b], wh.x, acc[b][0]));
        acc[b][1] = fmaf(s1, wi.y, fmaf(s[b], wh.y, acc[b][1]));
        acc[b][2] = fmaf(s1, wi.z, fmaf(s[b], wh.z, acc[b][2]));
        acc[b][3] = fmaf(s1, wi.w, fmaf(s[b], wh.w, acc[b][3]));
      }
    }
#pragma unroll
    for (int b = 0; b < NB; b++) {
      float ig = sigm(acc[b][0]), fg = sigm(acc[b][1]);
      float gg = tanhf(acc[b][2]), og = sigm(acc[b][3]);
      float sn = fmaf(fg, syn[b], ig * gg);
      float rst = (mem[b] > thr2) ? thr2 : 0.0f;
      float mn = fmaf(og, tanhf(sn), -rst);
      syn[b] = sn;
      mem[b] = mn;
      sb8[b] |= (mn > thr2) ? (1u << t) : 0u;  // record spk2 bit; replay in epilogue
    }
  }

  // extra step: input = final mem1 (dense). Keeps readlane form (4% of work)
  // so the fmaf interleave order stays identical to R5 (bit-exact).
  float m1[NB];
#pragma unroll
  for (int b = 0; b < NB; b++) m1[b] = mem1_in[(size_t)(wb + b) * 64 + lane];
  float acc[NB][4];
#pragma unroll
  for (int b = 0; b < NB; b++) {
#pragma unroll
    for (int q = 0; q < 4; q++) acc[b][q] = b2q[q];
  }
#pragma unroll 4
  for (int m = 0; m < 64; m++) {
    float4 wi = Pih[m][lane];
    float4 wh = Phh[m][lane];
#pragma unroll
    for (int b = 0; b < NB; b++) {
      float s1 = bcastf(m1[b], m);
      float s2 = bcastf(mem[b], m);
      acc[b][0] = fmaf(s1, wi.x, fmaf(s2, wh.x, acc[b][0]));
      acc[b][1] = fmaf(s1, wi.y, fmaf(s2, wh.y, acc[b][1]));
      acc[b][2] = fmaf(s1, wi.z, fmaf(s2, wh.z, acc[b][2]));
      acc[b][3] = fmaf(s1, wi.w, fmaf(s2, wh.w, acc[b][3]));
    }
  }
  // epilogue: replay p0/p1 accumulation (same fmaf order as R4/R5) from bits.
  float p0[NB], p1[NB];
#pragma unroll
  for (int b = 0; b < NB; b++) { p0[b] = 0.0f; p1[b] = 0.0f; }
#pragma unroll 4
  for (int t = 0; t < TT; t++) {
    float w0 = Wout[t * 64 + lane];
    float w1 = Wout[1664 + t * 64 + lane];
#pragma unroll
    for (int b = 0; b < NB; b++) {
      float sf = ((sb8[b] >> t) & 1u) ? 1.0f : 0.0f;
      p0[b] = fmaf(sf, w0, p0[b]);
      p1[b] = fmaf(sf, w1, p1[b]);
    }
  }
  float wA0 = Wout[1536 + lane], wA1 = Wout[1664 + 1536 + lane];  // spk2_last
  float wB0 = Wout[1600 + lane], wB1 = Wout[1664 + 1600 + lane];  // mem2 final
  float bo0 = bout[0], bo1 = bout[1];
#pragma unroll
  for (int b = 0; b < NB; b++) {
    float ig = sigm(acc[b][0]), fg = sigm(acc[b][1]);
    float gg = tanhf(acc[b][2]), og = sigm(acc[b][3]);
    float sn = fmaf(fg, syn[b], ig * gg);
    float rst = (mem[b] > thr2) ? thr2 : 0.0f;
    float mn = fmaf(og, tanhf(sn), -rst);
    float sf = (mn > thr2) ? 1.0f : 0.0f;
    p0[b] = fmaf(sf, wA0, p0[b]);
    p1[b] = fmaf(sf, wA1, p1[b]);
    p0[b] = fmaf(mn, wB0, p0[b]);
    p1[b] = fmaf(mn, wB1, p1[b]);
  }
  // cross-lane reduce; wsum leaves the full sum in ALL lanes (uniform),
  // so lane 2b / 2b+1 just keep their own output via predicated assign.
  float vout = 0.0f;
#pragma unroll
  for (int b = 0; b < NB; b++) {
    float r0 = wsum(p0[b]);
    float r1 = wsum(p1[b]);
    if (lane == 2 * b) vout = r0;
    if (lane == 2 * b + 1) vout = r1;
  }
  if (lane < 2 * NB)
    out[(size_t)wb * 2 + lane] = vout + ((lane & 1) ? bo1 : bo0);
}

extern "C" void kernel_launch(void* const* d_in, const int* in_sizes, int n_in,
                              void* d_out, int out_size, void* d_ws, size_t ws_size,
                              hipStream_t stream) {
  const float* x = (const float*)d_in[0];
  const float* Wih1 = (const float*)d_in[1];
  const float* Whh1 = (const float*)d_in[2];
  const float* bih1 = (const float*)d_in[3];
  const float* bhh1 = (const float*)d_in[4];
  const float* thr1 = (const float*)d_in[5];
  const float* Wih2 = (const float*)d_in[6];
  const float* Whh2 = (const float*)d_in[7];
  const float* bih2 = (const float*)d_in[8];
  const float* bhh2 = (const float*)d_in[9];
  const float* thr2 = (const float*)d_in[10];
  const float* Wout = (const float*)d_in[11];
  const float* bout = (const float*)d_in[12];

  unsigned long long* spk = (unsigned long long*)d_ws;
  float* mem1 = (float*)((char*)d_ws + (size_t)TT * BB * 8);

  const int grid = BB / (8 * NB);  // 1024 blocks of 512 threads (8 waves x 8 batches)
  snn_pass1<<<grid, 512, 0, stream>>>(x, Wih1, Whh1, bih1, bhh1, thr1, spk, mem1);
  snn_pass2<<<grid, 512, 0, stream>>>(Wih2, Whh2, bih2, bhh2, thr2, Wout, bout,
                                      spk, mem1, (float*)d_out);
}

// Round 7
// 2366.727 us; speedup vs baseline: 1.4613x; 1.1415x over previous
//
#include <hip/hip_runtime.h>
#include <cstdint>
#include <cstddef>

// SNN_53618371723788: 2-layer SLSTM, B=65536, T=24, H=64, fp32.
// Pass 1: layer-1 recurrence, emits spike bitmasks (ballot) + final mem1 to d_ws.
// Pass 2: layer-2 recurrence (spikes as SGPR bitmasks) + extra step + fused Wout GEMV.
// d_ws usage: 24*65536*8 B spike masks + 65536*64*4 B mem1 = 29,360,128 B.
//
// R7: pass2 at 1024 threads / 16 waves / 160 KB LDS -> 4 waves/SIMD (was 2).
// R6 evidence: pass1 (4 waves/SIMD) runs at 1.9x its FMA floor, pass2 (2
// waves/SIMD) at 3.2x -- latency-hiding deficit, not instruction count.
// __launch_bounds__(1024,4) keeps the 128-VGPR budget >= the 88 allocated.

#define BB 65536
#define TT 24
#define NB 8  // batch elements per wave

__device__ __forceinline__ float bcastf(float v, int l) {
  return __int_as_float(__builtin_amdgcn_readlane(__float_as_int(v), l));
}
__device__ __forceinline__ float sigm(float v) { return 1.0f / (1.0f + expf(-v)); }
__device__ __forceinline__ float wsum(float v) {
#pragma unroll
  for (int o = 32; o > 0; o >>= 1) v += __shfl_xor(v, o);
  return v;
}

__global__ __launch_bounds__(512, 4) void snn_pass1(
    const float* __restrict__ x, const float* __restrict__ Wih1,
    const float* __restrict__ Whh1, const float* __restrict__ bih1,
    const float* __restrict__ bhh1, const float* __restrict__ thr1p,
    unsigned long long* __restrict__ spk_out, float* __restrict__ mem1_out) {
  // P1[m][j] = {Whh1[j][m], Whh1[64+j][m], Whh1[128+j][m], Whh1[192+j][m]}
  __shared__ float4 P1[64][64];     // 64 KB
  __shared__ float stM[8][64][NB];  // 16 KB: per-wave state broadcast strip
  int tid = threadIdx.x;
  for (int idx = tid; idx < 16384; idx += 512) {
    int k = idx >> 6, m = idx & 63;
    ((float*)&P1[m][k & 63])[k >> 6] = Whh1[idx];
  }
  __syncthreads();
  int lane = tid & 63, wave = tid >> 6;
  int wb = (blockIdx.x * 8 + wave) * NB;  // first batch of this wave
  float thr1 = thr1p[0];
  float b1q[4], wq[4];
#pragma unroll
  for (int q = 0; q < 4; q++) {
    b1q[q] = bih1[q * 64 + lane] + bhh1[q * 64 + lane];
    wq[q] = Wih1[q * 64 + lane];
  }
  float syn[NB], mem[NB];
#pragma unroll
  for (int b = 0; b < NB; b++) { syn[b] = 0.0f; mem[b] = 0.0f; }

  for (int t = 0; t < TT; t++) {
    // stage this wave's mem state: lane j holds neuron j for all 8 batches
#pragma unroll
    for (int b = 0; b < NB; b++) stM[wave][lane][b] = mem[b];
    float acc[NB][4];
#pragma unroll
    for (int b = 0; b < NB; b++) {
      float xbt = x[(wb + b) * TT + t];
#pragma unroll
      for (int q = 0; q < 4; q++) acc[b][q] = fmaf(xbt, wq[q], b1q[q]);
    }
#pragma unroll 8
    for (int m = 0; m < 64; m++) {
      float4 w = P1[m][lane];  // per-lane weights (ds_read_b128)
      float4 sa = *(const float4*)&stM[wave][m][0];  // broadcast: same addr all lanes
      float4 sb = *(const float4*)&stM[wave][m][4];
      float s[NB] = {sa.x, sa.y, sa.z, sa.w, sb.x, sb.y, sb.z, sb.w};
#pragma unroll
      for (int b = 0; b < NB; b++) {
        acc[b][0] = fmaf(s[b], w.x, acc[b][0]);
        acc[b][1] = fmaf(s[b], w.y, acc[b][1]);
        acc[b][2] = fmaf(s[b], w.z, acc[b][2]);
        acc[b][3] = fmaf(s[b], w.w, acc[b][3]);
      }
    }
    unsigned long long myspk = 0;  // lane b keeps batch b's ballot (uniform value)
#pragma unroll
    for (int b = 0; b < NB; b++) {
      float ig = sigm(acc[b][0]), fg = sigm(acc[b][1]);
      float gg = tanhf(acc[b][2]), og = sigm(acc[b][3]);
      float sn = fmaf(fg, syn[b], ig * gg);
      float rst = (mem[b] > thr1) ? thr1 : 0.0f;  // reset uses OLD mem
      float mn = fmaf(og, tanhf(sn), -rst);
      syn[b] = sn;
      mem[b] = mn;
      unsigned long long msk = __ballot(mn > thr1);  // wave-uniform
      if (lane == b) myspk = msk;
    }
    if (lane < NB)
      spk_out[(size_t)t * BB + wb + lane] = myspk;
  }
#pragma unroll
  for (int b = 0; b < NB; b++)
    mem1_out[(size_t)(wb + b) * 64 + lane] = mem[b];
}

__global__ __launch_bounds__(1024, 4) void snn_pass2(
    const float* __restrict__ Wih2, const float* __restrict__ Whh2,
    const float* __restrict__ bih2, const float* __restrict__ bhh2,
    const float* __restrict__ thr2p, const float* __restrict__ Wout,
    const float* __restrict__ bout,
    const unsigned long long* __restrict__ spk_in,
    const float* __restrict__ mem1_in, float* __restrict__ out) {
  __shared__ float4 Pih[64][64];     // 64 KB
  __shared__ float4 Phh[64][64];     // 64 KB
  __shared__ float stM[16][64][NB];  // 32 KB -> 160 KB total (1 block/CU, 16 waves)
  int tid = threadIdx.x;
  for (int idx = tid; idx < 16384; idx += 1024) {
    int k = idx >> 6, m = idx & 63;
    ((float*)&Pih[m][k & 63])[k >> 6] = Wih2[idx];
    ((float*)&Phh[m][k & 63])[k >> 6] = Whh2[idx];
  }
  __syncthreads();
  int lane = tid & 63, wave = tid >> 6;
  int wb = (blockIdx.x * 16 + wave) * NB;
  float thr2 = thr2p[0];
  float b2q[4];
#pragma unroll
  for (int q = 0; q < 4; q++) b2q[q] = bih2[q * 64 + lane] + bhh2[q * 64 + lane];
  float syn[NB], mem[NB];
  unsigned sb8[NB];  // per-lane spike history of THIS lane's neuron, bit t
#pragma unroll
  for (int b = 0; b < NB; b++) { syn[b] = 0.0f; mem[b] = 0.0f; sb8[b] = 0u; }

  for (int t = 0; t < TT; t++) {
    // spike masks are wave-uniform -> SGPRs (SALU bit extract, co-issues)
    unsigned mlo[NB], mhi[NB];
#pragma unroll
    for (int b = 0; b < NB; b++) {
      unsigned long long v = spk_in[(size_t)t * BB + wb + b];
      mlo[b] = __builtin_amdgcn_readfirstlane((unsigned)v);
      mhi[b] = __builtin_amdgcn_readfirstlane((unsigned)(v >> 32));
    }
    // stage mem state for LDS broadcast
#pragma unroll
    for (int b = 0; b < NB; b++) stM[wave][lane][b] = mem[b];
    float acc[NB][4];
#pragma unroll
    for (int b = 0; b < NB; b++) {
#pragma unroll
      for (int q = 0; q < 4; q++) acc[b][q] = b2q[q];
    }
#pragma unroll 4
    for (int m = 0; m < 64; m++) {
      float4 wi = Pih[m][lane];
      float4 wh = Phh[m][lane];
      float4 sa = *(const float4*)&stM[wave][m][0];  // broadcast reads
      float4 sbv = *(const float4*)&stM[wave][m][4];
      float s[NB] = {sa.x, sa.y, sa.z, sa.w, sbv.x, sbv.y, sbv.z, sbv.w};
#pragma unroll
      for (int b = 0; b < NB; b++) {
        unsigned bits = (m < 32) ? mlo[b] : mhi[b];          // s_cselect
        float s1 = ((bits >> (m & 31)) & 1u) ? 1.0f : 0.0f;  // SALU select
        acc[b][0] = fmaf(s1, wi.x, fmaf(s[b], wh.x, acc[b][0]));
        acc[b][1] = fmaf(s1, wi.y, fmaf(s[b], wh.y, acc[b][1]));
        acc[b][2] = fmaf(s1, wi.z, fmaf(s[b], wh.z, acc[b][2]));
        acc[b][3] = fmaf(s1, wi.w, fmaf(s[b], wh.w, acc[b][3]));
      }
    }
#pragma unroll
    for (int b = 0; b < NB; b++) {
      float ig = sigm(acc[b][0]), fg = sigm(acc[b][1]);
      float gg = tanhf(acc[b][2]), og = sigm(acc[b][3]);
      float sn = fmaf(fg, syn[b], ig * gg);
      float rst = (mem[b] > thr2) ? thr2 : 0.0f;
      float mn = fmaf(og, tanhf(sn), -rst);
      syn[b] = sn;
      mem[b] = mn;
      sb8[b] |= (mn > thr2) ? (1u << t) : 0u;  // record spk2 bit; replay in epilogue
    }
  }

  // extra step: input = final mem1 (dense). Keeps readlane form (4% of work)
  // so the fmaf interleave order stays identical to R6 (bit-exact).
  float m1[NB];
#pragma unroll
  for (int b = 0; b < NB; b++) m1[b] = mem1_in[(size_t)(wb + b) * 64 + lane];
  float acc[NB][4];
#pragma unroll
  for (int b = 0; b < NB; b++) {
#pragma unroll
    for (int q = 0; q < 4; q++) acc[b][q] = b2q[q];
  }
#pragma unroll 4
  for (int m = 0; m < 64; m++) {
    float4 wi = Pih[m][lane];
    float4 wh = Phh[m][lane];
#pragma unroll
    for (int b = 0; b < NB; b++) {
      float s1 = bcastf(m1[b], m);
      float s2 = bcastf(mem[b], m);
      acc[b][0] = fmaf(s1, wi.x, fmaf(s2, wh.x, acc[b][0]));
      acc[b][1] = fmaf(s1, wi.y, fmaf(s2, wh.y, acc[b][1]));
      acc[b][2] = fmaf(s1, wi.z, fmaf(s2, wh.z, acc[b][2]));
      acc[b][3] = fmaf(s1, wi.w, fmaf(s2, wh.w, acc[b][3]));
    }
  }
  // epilogue: replay p0/p1 accumulation (same fmaf order as before) from bits.
  float p0[NB], p1[NB];
#pragma unroll
  for (int b = 0; b < NB; b++) { p0[b] = 0.0f; p1[b] = 0.0f; }
#pragma unroll 4
  for (int t = 0; t < TT; t++) {
    float w0 = Wout[t * 64 + lane];
    float w1 = Wout[1664 + t * 64 + lane];
#pragma unroll
    for (int b = 0; b < NB; b++) {
      float sf = ((sb8[b] >> t) & 1u) ? 1.0f : 0.0f;
      p0[b] = fmaf(sf, w0, p0[b]);
      p1[b] = fmaf(sf, w1, p1[b]);
    }
  }
  float wA0 = Wout[1536 + lane], wA1 = Wout[1664 + 1536 + lane];  // spk2_last
  float wB0 = Wout[1600 + lane], wB1 = Wout[1664 + 1600 + lane];  // mem2 final
  float bo0 = bout[0], bo1 = bout[1];
#pragma unroll
  for (int b = 0; b < NB; b++) {
    float ig = sigm(acc[b][0]), fg = sigm(acc[b][1]);
    float gg = tanhf(acc[b][2]), og = sigm(acc[b][3]);
    float sn = fmaf(fg, syn[b], ig * gg);
    float rst = (mem[b] > thr2) ? thr2 : 0.0f;
    float mn = fmaf(og, tanhf(sn), -rst);
    float sf = (mn > thr2) ? 1.0f : 0.0f;
    p0[b] = fmaf(sf, wA0, p0[b]);
    p1[b] = fmaf(sf, wA1, p1[b]);
    p0[b] = fmaf(mn, wB0, p0[b]);
    p1[b] = fmaf(mn, wB1, p1[b]);
  }
  // cross-lane reduce; wsum leaves the full sum in ALL lanes (uniform),
  // so lane 2b / 2b+1 just keep their own output via predicated assign.
  float vout = 0.0f;
#pragma unroll
  for (int b = 0; b < NB; b++) {
    float r0 = wsum(p0[b]);
    float r1 = wsum(p1[b]);
    if (lane == 2 * b) vout = r0;
    if (lane == 2 * b + 1) vout = r1;
  }
  if (lane < 2 * NB)
    out[(size_t)wb * 2 + lane] = vout + ((lane & 1) ? bo1 : bo0);
}

extern "C" void kernel_launch(void* const* d_in, const int* in_sizes, int n_in,
                              void* d_out, int out_size, void* d_ws, size_t ws_size,
                              hipStream_t stream) {
  const float* x = (const float*)d_in[0];
  const float* Wih1 = (const float*)d_in[1];
  const float* Whh1 = (const float*)d_in[2];
  const float* bih1 = (const float*)d_in[3];
  const float* bhh1 = (const float*)d_in[4];
  const float* thr1 = (const float*)d_in[5];
  const float* Wih2 = (const float*)d_in[6];
  const float* Whh2 = (const float*)d_in[7];
  const float* bih2 = (const float*)d_in[8];
  const float* bhh2 = (const float*)d_in[9];
  const float* thr2 = (const float*)d_in[10];
  const float* Wout = (const float*)d_in[11];
  const float* bout = (const float*)d_in[12];

  unsigned long long* spk = (unsigned long long*)d_ws;
  float* mem1 = (float*)((char*)d_ws + (size_t)TT * BB * 8);

  snn_pass1<<<BB / (8 * NB), 512, 0, stream>>>(x, Wih1, Whh1, bih1, bhh1, thr1,
                                               spk, mem1);
  snn_pass2<<<BB / (16 * NB), 1024, 0, stream>>>(Wih2, Whh2, bih2, bhh2, thr2,
                                                 Wout, bout, spk, mem1,
                                                 (float*)d_out);
}

// Round 8
// 2333.338 us; speedup vs baseline: 1.4822x; 1.0143x over previous
//
#include <hip/hip_runtime.h>
#include <cstdint>
#include <cstddef>

// SNN_53618371723788: 2-layer SLSTM, B=65536, T=24, H=64, fp32.
// Pass 1: layer-1 recurrence, emits spike bitmasks (ballot) + final mem1 to d_ws.
// Pass 2: layer-2 recurrence (spikes as SGPR bitmasks) + extra step + fused Wout GEMV.
// d_ws usage: 24*65536*8 B spike masks + 65536*64*4 B mem1 = 29,360,128 B.
//
// R8: pin amdgpu_waves_per_eu(4,4) on both kernels. Evidence trail: allocator
// targets 8 waves/EU at 1024 threads (VGPR=64 in R2/R7) regardless of the
// 160 KB LDS capping occupancy at 4 waves/EU; ~100 live values in 64 regs =
// AGPR shuffling = ~2.5x VALU inflation. waves_per_eu(4,4) forces the
// 128-VGPR budget that matches the LDS-imposed occupancy.

#define BB 65536
#define TT 24
#define NB 8  // batch elements per wave

__device__ __forceinline__ float bcastf(float v, int l) {
  return __int_as_float(__builtin_amdgcn_readlane(__float_as_int(v), l));
}
__device__ __forceinline__ float sigm(float v) { return 1.0f / (1.0f + expf(-v)); }
__device__ __forceinline__ float wsum(float v) {
#pragma unroll
  for (int o = 32; o > 0; o >>= 1) v += __shfl_xor(v, o);
  return v;
}

__global__ __attribute__((amdgpu_waves_per_eu(4, 4))) __launch_bounds__(512)
void snn_pass1(
    const float* __restrict__ x, const float* __restrict__ Wih1,
    const float* __restrict__ Whh1, const float* __restrict__ bih1,
    const float* __restrict__ bhh1, const float* __restrict__ thr1p,
    unsigned long long* __restrict__ spk_out, float* __restrict__ mem1_out) {
  // P1[m][j] = {Whh1[j][m], Whh1[64+j][m], Whh1[128+j][m], Whh1[192+j][m]}
  __shared__ float4 P1[64][64];     // 64 KB
  __shared__ float stM[8][64][NB];  // 16 KB: per-wave state broadcast strip
  int tid = threadIdx.x;
  for (int idx = tid; idx < 16384; idx += 512) {
    int k = idx >> 6, m = idx & 63;
    ((float*)&P1[m][k & 63])[k >> 6] = Whh1[idx];
  }
  __syncthreads();
  int lane = tid & 63, wave = tid >> 6;
  int wb = (blockIdx.x * 8 + wave) * NB;  // first batch of this wave
  float thr1 = thr1p[0];
  float b1q[4], wq[4];
#pragma unroll
  for (int q = 0; q < 4; q++) {
    b1q[q] = bih1[q * 64 + lane] + bhh1[q * 64 + lane];
    wq[q] = Wih1[q * 64 + lane];
  }
  float syn[NB], mem[NB];
#pragma unroll
  for (int b = 0; b < NB; b++) { syn[b] = 0.0f; mem[b] = 0.0f; }

  for (int t = 0; t < TT; t++) {
    // stage this wave's mem state: lane j holds neuron j for all 8 batches
#pragma unroll
    for (int b = 0; b < NB; b++) stM[wave][lane][b] = mem[b];
    float acc[NB][4];
#pragma unroll
    for (int b = 0; b < NB; b++) {
      float xbt = x[(wb + b) * TT + t];
#pragma unroll
      for (int q = 0; q < 4; q++) acc[b][q] = fmaf(xbt, wq[q], b1q[q]);
    }
#pragma unroll 8
    for (int m = 0; m < 64; m++) {
      float4 w = P1[m][lane];  // per-lane weights (ds_read_b128)
      float4 sa = *(const float4*)&stM[wave][m][0];  // broadcast: same addr all lanes
      float4 sb = *(const float4*)&stM[wave][m][4];
      float s[NB] = {sa.x, sa.y, sa.z, sa.w, sb.x, sb.y, sb.z, sb.w};
#pragma unroll
      for (int b = 0; b < NB; b++) {
        acc[b][0] = fmaf(s[b], w.x, acc[b][0]);
        acc[b][1] = fmaf(s[b], w.y, acc[b][1]);
        acc[b][2] = fmaf(s[b], w.z, acc[b][2]);
        acc[b][3] = fmaf(s[b], w.w, acc[b][3]);
      }
    }
    unsigned long long myspk = 0;  // lane b keeps batch b's ballot (uniform value)
#pragma unroll
    for (int b = 0; b < NB; b++) {
      float ig = sigm(acc[b][0]), fg = sigm(acc[b][1]);
      float gg = tanhf(acc[b][2]), og = sigm(acc[b][3]);
      float sn = fmaf(fg, syn[b], ig * gg);
      float rst = (mem[b] > thr1) ? thr1 : 0.0f;  // reset uses OLD mem
      float mn = fmaf(og, tanhf(sn), -rst);
      syn[b] = sn;
      mem[b] = mn;
      unsigned long long msk = __ballot(mn > thr1);  // wave-uniform
      if (lane == b) myspk = msk;
    }
    if (lane < NB)
      spk_out[(size_t)t * BB + wb + lane] = myspk;
  }
#pragma unroll
  for (int b = 0; b < NB; b++)
    mem1_out[(size_t)(wb + b) * 64 + lane] = mem[b];
}

__global__ __attribute__((amdgpu_waves_per_eu(4, 4))) __launch_bounds__(1024)
void snn_pass2(
    const float* __restrict__ Wih2, const float* __restrict__ Whh2,
    const float* __restrict__ bih2, const float* __restrict__ bhh2,
    const float* __restrict__ thr2p, const float* __restrict__ Wout,
    const float* __restrict__ bout,
    const unsigned long long* __restrict__ spk_in,
    const float* __restrict__ mem1_in, float* __restrict__ out) {
  __shared__ float4 Pih[64][64];     // 64 KB
  __shared__ float4 Phh[64][64];     // 64 KB
  __shared__ float stM[16][64][NB];  // 32 KB -> 160 KB total (1 block/CU, 16 waves)
  int tid = threadIdx.x;
  for (int idx = tid; idx < 16384; idx += 1024) {
    int k = idx >> 6, m = idx & 63;
    ((float*)&Pih[m][k & 63])[k >> 6] = Wih2[idx];
    ((float*)&Phh[m][k & 63])[k >> 6] = Whh2[idx];
  }
  __syncthreads();
  int lane = tid & 63, wave = tid >> 6;
  int wb = (blockIdx.x * 16 + wave) * NB;
  float thr2 = thr2p[0];
  float b2q[4];
#pragma unroll
  for (int q = 0; q < 4; q++) b2q[q] = bih2[q * 64 + lane] + bhh2[q * 64 + lane];
  float syn[NB], mem[NB];
  unsigned sb8[NB];  // per-lane spike history of THIS lane's neuron, bit t
#pragma unroll
  for (int b = 0; b < NB; b++) { syn[b] = 0.0f; mem[b] = 0.0f; sb8[b] = 0u; }

  for (int t = 0; t < TT; t++) {
    // spike masks are wave-uniform -> SGPRs (SALU bit extract, co-issues)
    unsigned mlo[NB], mhi[NB];
#pragma unroll
    for (int b = 0; b < NB; b++) {
      unsigned long long v = spk_in[(size_t)t * BB + wb + b];
      mlo[b] = __builtin_amdgcn_readfirstlane((unsigned)v);
      mhi[b] = __builtin_amdgcn_readfirstlane((unsigned)(v >> 32));
    }
    // stage mem state for LDS broadcast
#pragma unroll
    for (int b = 0; b < NB; b++) stM[wave][lane][b] = mem[b];
    float acc[NB][4];
#pragma unroll
    for (int b = 0; b < NB; b++) {
#pragma unroll
      for (int q = 0; q < 4; q++) acc[b][q] = b2q[q];
    }
#pragma unroll 4
    for (int m = 0; m < 64; m++) {
      float4 wi = Pih[m][lane];
      float4 wh = Phh[m][lane];
      float4 sa = *(const float4*)&stM[wave][m][0];  // broadcast reads
      float4 sbv = *(const float4*)&stM[wave][m][4];
      float s[NB] = {sa.x, sa.y, sa.z, sa.w, sbv.x, sbv.y, sbv.z, sbv.w};
#pragma unroll
      for (int b = 0; b < NB; b++) {
        unsigned bits = (m < 32) ? mlo[b] : mhi[b];          // s_cselect
        float s1 = ((bits >> (m & 31)) & 1u) ? 1.0f : 0.0f;  // SALU select
        acc[b][0] = fmaf(s1, wi.x, fmaf(s[b], wh.x, acc[b][0]));
        acc[b][1] = fmaf(s1, wi.y, fmaf(s[b], wh.y, acc[b][1]));
        acc[b][2] = fmaf(s1, wi.z, fmaf(s[b], wh.z, acc[b][2]));
        acc[b][3] = fmaf(s1, wi.w, fmaf(s[b], wh.w, acc[b][3]));
      }
    }
#pragma unroll
    for (int b = 0; b < NB; b++) {
      float ig = sigm(acc[b][0]), fg = sigm(acc[b][1]);
      float gg = tanhf(acc[b][2]), og = sigm(acc[b][3]);
      float sn = fmaf(fg, syn[b], ig * gg);
      float rst = (mem[b] > thr2) ? thr2 : 0.0f;
      float mn = fmaf(og, tanhf(sn), -rst);
      syn[b] = sn;
      mem[b] = mn;
      sb8[b] |= (mn > thr2) ? (1u << t) : 0u;  // record spk2 bit; replay in epilogue
    }
  }

  // extra step: input = final mem1 (dense). Keeps readlane form (4% of work)
  // so the fmaf interleave order stays identical (bit-exact).
  float m1[NB];
#pragma unroll
  for (int b = 0; b < NB; b++) m1[b] = mem1_in[(size_t)(wb + b) * 64 + lane];
  float acc[NB][4];
#pragma unroll
  for (int b = 0; b < NB; b++) {
#pragma unroll
    for (int q = 0; q < 4; q++) acc[b][q] = b2q[q];
  }
#pragma unroll 4
  for (int m = 0; m < 64; m++) {
    float4 wi = Pih[m][lane];
    float4 wh = Phh[m][lane];
#pragma unroll
    for (int b = 0; b < NB; b++) {
      float s1 = bcastf(m1[b], m);
      float s2 = bcastf(mem[b], m);
      acc[b][0] = fmaf(s1, wi.x, fmaf(s2, wh.x, acc[b][0]));
      acc[b][1] = fmaf(s1, wi.y, fmaf(s2, wh.y, acc[b][1]));
      acc[b][2] = fmaf(s1, wi.z, fmaf(s2, wh.z, acc[b][2]));
      acc[b][3] = fmaf(s1, wi.w, fmaf(s2, wh.w, acc[b][3]));
    }
  }
  // epilogue: replay p0/p1 accumulation (same fmaf order as before) from bits.
  float p0[NB], p1[NB];
#pragma unroll
  for (int b = 0; b < NB; b++) { p0[b] = 0.0f; p1[b] = 0.0f; }
#pragma unroll 4
  for (int t = 0; t < TT; t++) {
    float w0 = Wout[t * 64 + lane];
    float w1 = Wout[1664 + t * 64 + lane];
#pragma unroll
    for (int b = 0; b < NB; b++) {
      float sf = ((sb8[b] >> t) & 1u) ? 1.0f : 0.0f;
      p0[b] = fmaf(sf, w0, p0[b]);
      p1[b] = fmaf(sf, w1, p1[b]);
    }
  }
  float wA0 = Wout[1536 + lane], wA1 = Wout[1664 + 1536 + lane];  // spk2_last
  float wB0 = Wout[1600 + lane], wB1 = Wout[1664 + 1600 + lane];  // mem2 final
  float bo0 = bout[0], bo1 = bout[1];
#pragma unroll
  for (int b = 0; b < NB; b++) {
    float ig = sigm(acc[b][0]), fg = sigm(acc[b][1]);
    float gg = tanhf(acc[b][2]), og = sigm(acc[b][3]);
    float sn = fmaf(fg, syn[b], ig * gg);
    float rst = (mem[b] > thr2) ? thr2 : 0.0f;
    float mn = fmaf(og, tanhf(sn), -rst);
    float sf = (mn > thr2) ? 1.0f : 0.0f;
    p0[b] = fmaf(sf, wA0, p0[b]);
    p1[b] = fmaf(sf, wA1, p1[b]);
    p0[b] = fmaf(mn, wB0, p0[b]);
    p1[b] = fmaf(mn, wB1, p1[b]);
  }
  // cross-lane reduce; wsum leaves the full sum in ALL lanes (uniform),
  // so lane 2b / 2b+1 just keep their own output via predicated assign.
  float vout = 0.0f;
#pragma unroll
  for (int b = 0; b < NB; b++) {
    float r0 = wsum(p0[b]);
    float r1 = wsum(p1[b]);
    if (lane == 2 * b) vout = r0;
    if (lane == 2 * b + 1) vout = r1;
  }
  if (lane < 2 * NB)
    out[(size_t)wb * 2 + lane] = vout + ((lane & 1) ? bo1 : bo0);
}

extern "C" void kernel_launch(void* const* d_in, const int* in_sizes, int n_in,
                              void* d_out, int out_size, void* d_ws, size_t ws_size,
                              hipStream_t stream) {
  const float* x = (const float*)d_in[0];
  const float* Wih1 = (const float*)d_in[1];
  const float* Whh1 = (const float*)d_in[2];
  const float* bih1 = (const float*)d_in[3];
  const float* bhh1 = (const float*)d_in[4];
  const float* thr1 = (const float*)d_in[5];
  const float* Wih2 = (const float*)d_in[6];
  const float* Whh2 = (const float*)d_in[7];
  const float* bih2 = (const float*)d_in[8];
  const float* bhh2 = (const float*)d_in[9];
  const float* thr2 = (const float*)d_in[10];
  const float* Wout = (const float*)d_in[11];
  const float* bout = (const float*)d_in[12];

  unsigned long long* spk = (unsigned long long*)d_ws;
  float* mem1 = (float*)((char*)d_ws + (size_t)TT * BB * 8);

  snn_pass1<<<BB / (8 * NB), 512, 0, stream>>>(x, Wih1, Whh1, bih1, bhh1, thr1,
                                               spk, mem1);
  snn_pass2<<<BB / (16 * NB), 1024, 0, stream>>>(Wih2, Whh2, bih2, bhh2, thr2,
                                                 Wout, bout, spk, mem1,
                                                 (float*)d_out);
}

// Round 9
// 1784.955 us; speedup vs baseline: 1.9376x; 1.3072x over previous
//
#include <hip/hip_runtime.h>
#include <cstdint>
#include <cstddef>

// SNN_53618371723788: 2-layer SLSTM, B=65536, T=24, H=64, fp32.
// Pass 1: layer-1 recurrence, emits spike bitmasks (ballot) + final mem1 to d_ws.
// Pass 2: layer-2 recurrence + extra step + fused Wout GEMV.
//
// R9: SPARSE spike matvec in pass2. The ih part multiplies by s1 in {0,1};
// fmaf(0,w,acc)==acc exactly, so only set bits matter. Dense ih cost was
// 2560 VALU/t (2048 FMA + 512 select); sparse costs ~5 VALU per set bit
// (addr + ds_read_b128 + 4 adds), wave-uniform control flow via SGPR masks
// (s_ff1_i32_b64), 2-deep pipelined to overlap LDS latency. hh part stays
// dense (mem is dense). Order change: ih adds now follow the hh sum
// (was interleaved per-m) -- few-ulp gate noise, same class as existing
// deviation from the np reference's GEMM order (passed 0.0 for 6 rounds).

#define BB 65536
#define TT 24
#define NB 8  // batch elements per wave

__device__ __forceinline__ float bcastf(float v, int l) {
  return __int_as_float(__builtin_amdgcn_readlane(__float_as_int(v), l));
}
__device__ __forceinline__ float sigm(float v) { return 1.0f / (1.0f + expf(-v)); }
__device__ __forceinline__ float wsum(float v) {
#pragma unroll
  for (int o = 32; o > 0; o >>= 1) v += __shfl_xor(v, o);
  return v;
}

__global__ __attribute__((amdgpu_waves_per_eu(4, 4))) __launch_bounds__(512)
void snn_pass1(
    const float* __restrict__ x, const float* __restrict__ Wih1,
    const float* __restrict__ Whh1, const float* __restrict__ bih1,
    const float* __restrict__ bhh1, const float* __restrict__ thr1p,
    unsigned long long* __restrict__ spk_out, float* __restrict__ mem1_out) {
  // P1[m][j] = {Whh1[j][m], Whh1[64+j][m], Whh1[128+j][m], Whh1[192+j][m]}
  __shared__ float4 P1[64][64];     // 64 KB
  __shared__ float stM[8][64][NB];  // 16 KB: per-wave state broadcast strip
  int tid = threadIdx.x;
  for (int idx = tid; idx < 16384; idx += 512) {
    int k = idx >> 6, m = idx & 63;
    ((float*)&P1[m][k & 63])[k >> 6] = Whh1[idx];
  }
  __syncthreads();
  int lane = tid & 63, wave = tid >> 6;
  int wb = (blockIdx.x * 8 + wave) * NB;  // first batch of this wave
  float thr1 = thr1p[0];
  float b1q[4], wq[4];
#pragma unroll
  for (int q = 0; q < 4; q++) {
    b1q[q] = bih1[q * 64 + lane] + bhh1[q * 64 + lane];
    wq[q] = Wih1[q * 64 + lane];
  }
  float syn[NB], mem[NB];
#pragma unroll
  for (int b = 0; b < NB; b++) { syn[b] = 0.0f; mem[b] = 0.0f; }

  for (int t = 0; t < TT; t++) {
    // stage this wave's mem state: lane j holds neuron j for all 8 batches
#pragma unroll
    for (int b = 0; b < NB; b++) stM[wave][lane][b] = mem[b];
    float acc[NB][4];
#pragma unroll
    for (int b = 0; b < NB; b++) {
      float xbt = x[(wb + b) * TT + t];
#pragma unroll
      for (int q = 0; q < 4; q++) acc[b][q] = fmaf(xbt, wq[q], b1q[q]);
    }
#pragma unroll 8
    for (int m = 0; m < 64; m++) {
      float4 w = P1[m][lane];  // per-lane weights (ds_read_b128)
      float4 sa = *(const float4*)&stM[wave][m][0];  // broadcast: same addr all lanes
      float4 sb = *(const float4*)&stM[wave][m][4];
      float s[NB] = {sa.x, sa.y, sa.z, sa.w, sb.x, sb.y, sb.z, sb.w};
#pragma unroll
      for (int b = 0; b < NB; b++) {
        acc[b][0] = fmaf(s[b], w.x, acc[b][0]);
        acc[b][1] = fmaf(s[b], w.y, acc[b][1]);
        acc[b][2] = fmaf(s[b], w.z, acc[b][2]);
        acc[b][3] = fmaf(s[b], w.w, acc[b][3]);
      }
    }
    unsigned long long myspk = 0;  // lane b keeps batch b's ballot (uniform value)
#pragma unroll
    for (int b = 0; b < NB; b++) {
      float ig = sigm(acc[b][0]), fg = sigm(acc[b][1]);
      float gg = tanhf(acc[b][2]), og = sigm(acc[b][3]);
      float sn = fmaf(fg, syn[b], ig * gg);
      float rst = (mem[b] > thr1) ? thr1 : 0.0f;  // reset uses OLD mem
      float mn = fmaf(og, tanhf(sn), -rst);
      syn[b] = sn;
      mem[b] = mn;
      unsigned long long msk = __ballot(mn > thr1);  // wave-uniform
      if (lane == b) myspk = msk;
    }
    if (lane < NB)
      spk_out[(size_t)t * BB + wb + lane] = myspk;
  }
#pragma unroll
  for (int b = 0; b < NB; b++)
    mem1_out[(size_t)(wb + b) * 64 + lane] = mem[b];
}

__global__ __attribute__((amdgpu_waves_per_eu(4, 4))) __launch_bounds__(1024)
void snn_pass2(
    const float* __restrict__ Wih2, const float* __restrict__ Whh2,
    const float* __restrict__ bih2, const float* __restrict__ bhh2,
    const float* __restrict__ thr2p, const float* __restrict__ Wout,
    const float* __restrict__ bout,
    const unsigned long long* __restrict__ spk_in,
    const float* __restrict__ mem1_in, float* __restrict__ out) {
  __shared__ float4 Pih[64][64];     // 64 KB
  __shared__ float4 Phh[64][64];     // 64 KB
  __shared__ float stM[16][64][NB];  // 32 KB -> 160 KB total (1 block/CU, 16 waves)
  int tid = threadIdx.x;
  for (int idx = tid; idx < 16384; idx += 1024) {
    int k = idx >> 6, m = idx & 63;
    ((float*)&Pih[m][k & 63])[k >> 6] = Wih2[idx];
    ((float*)&Phh[m][k & 63])[k >> 6] = Whh2[idx];
  }
  __syncthreads();
  int lane = tid & 63, wave = tid >> 6;
  int wb = (blockIdx.x * 16 + wave) * NB;
  float thr2 = thr2p[0];
  float b2q[4];
#pragma unroll
  for (int q = 0; q < 4; q++) b2q[q] = bih2[q * 64 + lane] + bhh2[q * 64 + lane];
  float syn[NB], mem[NB];
  unsigned sb8[NB];  // per-lane spike history of THIS lane's neuron, bit t
#pragma unroll
  for (int b = 0; b < NB; b++) { syn[b] = 0.0f; mem[b] = 0.0f; sb8[b] = 0u; }

  for (int t = 0; t < TT; t++) {
    // spike masks -> SGPR u64 (wave-uniform)
    unsigned long long mk[NB];
#pragma unroll
    for (int b = 0; b < NB; b++) {
      unsigned long long v = spk_in[(size_t)t * BB + wb + b];
      unsigned lo = __builtin_amdgcn_readfirstlane((unsigned)v);
      unsigned hi = __builtin_amdgcn_readfirstlane((unsigned)(v >> 32));
      mk[b] = ((unsigned long long)hi << 32) | (unsigned long long)lo;
    }
    // stage mem state for LDS broadcast
#pragma unroll
    for (int b = 0; b < NB; b++) stM[wave][lane][b] = mem[b];
    float acc[NB][4];
#pragma unroll
    for (int b = 0; b < NB; b++) {
#pragma unroll
      for (int q = 0; q < 4; q++) acc[b][q] = b2q[q];
    }
    // dense hh part (mem is dense)
#pragma unroll 4
    for (int m = 0; m < 64; m++) {
      float4 wh = Phh[m][lane];
      float4 sa = *(const float4*)&stM[wave][m][0];  // broadcast reads
      float4 sbv = *(const float4*)&stM[wave][m][4];
      float s[NB] = {sa.x, sa.y, sa.z, sa.w, sbv.x, sbv.y, sbv.z, sbv.w};
#pragma unroll
      for (int b = 0; b < NB; b++) {
        acc[b][0] = fmaf(s[b], wh.x, acc[b][0]);
        acc[b][1] = fmaf(s[b], wh.y, acc[b][1]);
        acc[b][2] = fmaf(s[b], wh.z, acc[b][2]);
        acc[b][3] = fmaf(s[b], wh.w, acc[b][3]);
      }
    }
    // sparse ih part: only set bits contribute (coefficient exactly 1.0).
    // Wave-uniform loop (mask in SGPRs), 2-deep pipeline to overlap ds_read.
#pragma unroll
    for (int b = 0; b < NB; b++) {
      unsigned long long k = mk[b];
      if (k) {
        int m0 = __builtin_ctzll(k);
        k &= k - 1;
        float4 r0 = Pih[m0][lane];
        while (k) {
          int m1 = __builtin_ctzll(k);
          k &= k - 1;
          float4 r1 = Pih[m1][lane];  // issue next read before consuming r0
          acc[b][0] += r0.x;
          acc[b][1] += r0.y;
          acc[b][2] += r0.z;
          acc[b][3] += r0.w;
          r0 = r1;
        }
        acc[b][0] += r0.x;
        acc[b][1] += r0.y;
        acc[b][2] += r0.z;
        acc[b][3] += r0.w;
      }
    }
#pragma unroll
    for (int b = 0; b < NB; b++) {
      float ig = sigm(acc[b][0]), fg = sigm(acc[b][1]);
      float gg = tanhf(acc[b][2]), og = sigm(acc[b][3]);
      float sn = fmaf(fg, syn[b], ig * gg);
      float rst = (mem[b] > thr2) ? thr2 : 0.0f;
      float mn = fmaf(og, tanhf(sn), -rst);
      syn[b] = sn;
      mem[b] = mn;
      sb8[b] |= (mn > thr2) ? (1u << t) : 0u;  // record spk2 bit; replay in epilogue
    }
  }

  // extra step: input = final mem1 (dense). Keeps readlane form (4% of work).
  float m1[NB];
#pragma unroll
  for (int b = 0; b < NB; b++) m1[b] = mem1_in[(size_t)(wb + b) * 64 + lane];
  float acc[NB][4];
#pragma unroll
  for (int b = 0; b < NB; b++) {
#pragma unroll
    for (int q = 0; q < 4; q++) acc[b][q] = b2q[q];
  }
#pragma unroll 4
  for (int m = 0; m < 64; m++) {
    float4 wi = Pih[m][lane];
    float4 wh = Phh[m][lane];
#pragma unroll
    for (int b = 0; b < NB; b++) {
      float s1 = bcastf(m1[b], m);
      float s2 = bcastf(mem[b], m);
      acc[b][0] = fmaf(s1, wi.x, fmaf(s2, wh.x, acc[b][0]));
      acc[b][1] = fmaf(s1, wi.y, fmaf(s2, wh.y, acc[b][1]));
      acc[b][2] = fmaf(s1, wi.z, fmaf(s2, wh.z, acc[b][2]));
      acc[b][3] = fmaf(s1, wi.w, fmaf(s2, wh.w, acc[b][3]));
    }
  }
  // epilogue: replay p0/p1 accumulation (same fmaf order as before) from bits.
  float p0[NB], p1[NB];
#pragma unroll
  for (int b = 0; b < NB; b++) { p0[b] = 0.0f; p1[b] = 0.0f; }
#pragma unroll 4
  for (int t = 0; t < TT; t++) {
    float w0 = Wout[t * 64 + lane];
    float w1 = Wout[1664 + t * 64 + lane];
#pragma unroll
    for (int b = 0; b < NB; b++) {
      float sf = ((sb8[b] >> t) & 1u) ? 1.0f : 0.0f;
      p0[b] = fmaf(sf, w0, p0[b]);
      p1[b] = fmaf(sf, w1, p1[b]);
    }
  }
  float wA0 = Wout[1536 + lane], wA1 = Wout[1664 + 1536 + lane];  // spk2_last
  float wB0 = Wout[1600 + lane], wB1 = Wout[1664 + 1600 + lane];  // mem2 final
  float bo0 = bout[0], bo1 = bout[1];
#pragma unroll
  for (int b = 0; b < NB; b++) {
    float ig = sigm(acc[b][0]), fg = sigm(acc[b][1]);
    float gg = tanhf(acc[b][2]), og = sigm(acc[b][3]);
    float sn = fmaf(fg, syn[b], ig * gg);
    float rst = (mem[b] > thr2) ? thr2 : 0.0f;
    float mn = fmaf(og, tanhf(sn), -rst);
    float sf = (mn > thr2) ? 1.0f : 0.0f;
    p0[b] = fmaf(sf, wA0, p0[b]);
    p1[b] = fmaf(sf, wA1, p1[b]);
    p0[b] = fmaf(mn, wB0, p0[b]);
    p1[b] = fmaf(mn, wB1, p1[b]);
  }
  // cross-lane reduce; wsum leaves the full sum in ALL lanes (uniform),
  // so lane 2b / 2b+1 just keep their own output via predicated assign.
  float vout = 0.0f;
#pragma unroll
  for (int b = 0; b < NB; b++) {
    float r0 = wsum(p0[b]);
    float r1 = wsum(p1[b]);
    if (lane == 2 * b) vout = r0;
    if (lane == 2 * b + 1) vout = r1;
  }
  if (lane < 2 * NB)
    out[(size_t)wb * 2 + lane] = vout + ((lane & 1) ? bo1 : bo0);
}

extern "C" void kernel_launch(void* const* d_in, const int* in_sizes, int n_in,
                              void* d_out, int out_size, void* d_ws, size_t ws_size,
                              hipStream_t stream) {
  const float* x = (const float*)d_in[0];
  const float* Wih1 = (const float*)d_in[1];
  const float* Whh1 = (const float*)d_in[2];
  const float* bih1 = (const float*)d_in[3];
  const float* bhh1 = (const float*)d_in[4];
  const float* thr1 = (const float*)d_in[5];
  const float* Wih2 = (const float*)d_in[6];
  const float* Whh2 = (const float*)d_in[7];
  const float* bih2 = (const float*)d_in[8];
  const float* bhh2 = (const float*)d_in[9];
  const float* thr2 = (const float*)d_in[10];
  const float* Wout = (const float*)d_in[11];
  const float* bout = (const float*)d_in[12];

  unsigned long long* spk = (unsigned long long*)d_ws;
  float* mem1 = (float*)((char*)d_ws + (size_t)TT * BB * 8);

  snn_pass1<<<BB / (8 * NB), 512, 0, stream>>>(x, Wih1, Whh1, bih1, bhh1, thr1,
                                               spk, mem1);
  snn_pass2<<<BB / (16 * NB), 1024, 0, stream>>>(Wih2, Whh2, bih2, bhh2, thr2,
                                                 Wout, bout, spk, mem1,
                                                 (float*)d_out);
}